// Round 8
// baseline (127.791 us; speedup 1.0000x reference)
//
#include <hip/hip_runtime.h>

// ClusterLoss fused kernel for MI355X (gfx950).  R15.
// Post-mortem R14 (43us, MfmaUtil 28%): two co-limiters vs the 16.6us MFMA
// floor: (1) B-stream L2 traffic 512 MB (every wave reads all 128KB of bws
// per 32-row tile) ~ 15us at L2 ceiling; (2) A-tile LDS round trip is serial
// latency although fragments are 8 contiguous floats of one row.
// R15: TROWS=64, each wave sweeps HALF the centers (512):
//   - arithmetic intensity doubles (32 MFMA per 64 B/lane of B), B L2
//     traffic halves to 256 MB;
//   - A fragments built DIRECTLY from global feats (row i2*16+m16, cols
//     kk*32+quad*8 -> two float4 -> 8 fp8 bytes); wave reads each element
//     exactly once; LDS staging + swizzle + lgkmcnt drain deleted;
//   - block = 4 waves = 2 tiles x 2 center-halves; cross-half argmax
//     combine via 1.3 KB static LDS + ONE __syncthreads per kernel;
//   - sumsq: lane-local over 32 elems + 2 quad-shuffles.
// Allocator rules (measured): 1024-thr block or min-waves>=2 pins 64 VGPR.
// Use (256,1). Spill tripwire = WRITE_SIZE.
// loss_n = 1 - 2 d na/nf + na^2 (fp32 scalars).

#define D 128
#define TROWS 64

typedef __attribute__((ext_vector_type(4))) float floatx4;
typedef __attribute__((ext_vector_type(2))) long long llx2;

template <bool HI>
__device__ __forceinline__ unsigned int pk_fp8(float a, float b, unsigned int old) {
    return (unsigned int)__builtin_amdgcn_cvt_pk_fp8_f32(a, b, (int)old, HI);
}

__device__ __forceinline__ float key_pack(float v, unsigned int inv_k) {
    unsigned int u = __builtin_bit_cast(unsigned int, v);
    unsigned int r = (0x3FFu & inv_k) | (~0x3FFu & u);   // v_bfi_b32
    return __builtin_bit_cast(float, r);
}

// ---- Prep: normalize centers -> fp8, scattered into frag-ordered bws ----
// bws byte layout: ((g*64 + lane)*4 + kk)*8 + b  ==  chat[g*16 + (lane&15)]
//                                                    [kk*32 + (lane>>4)*8 + b]
__global__ void prep_centers(const float* __restrict__ centers,
                             unsigned char* __restrict__ bws,
                             float* __restrict__ cnorm) {
    const int k = blockIdx.x;
    const int t = threadIdx.x;            // 128 threads, one per dim
    float v = centers[(size_t)k * D + t];
    float s = v * v;
    #pragma unroll
    for (int m = 1; m <= 32; m <<= 1) s += __shfl_xor(s, m);
    __shared__ float ws2[2];
    if ((t & 63) == 0) ws2[t >> 6] = s;
    __syncthreads();
    float total = ws2[0] + ws2[1];
    float n = sqrtf(total);
    float q = v / fmaxf(n, 1e-12f);
    const int kk = t >> 5, quad = (t >> 3) & 3, b = t & 7;
    const int lane = (k & 15) + (quad << 4);
    const int g = k >> 4;
    bws[(((size_t)g * 64 + lane) * 4 + kk) * 8 + b] =
        (unsigned char)(pk_fp8<false>(q, q, 0u) & 0xFFu);
    if (t == 0) cnorm[k] = n;
}

// ---- Main: wave-autonomous, one barrier total ----
__global__ __launch_bounds__(256, 1) void cluster_main(
    const float* __restrict__ feats,        // [N][128] fp32
    const unsigned char* __restrict__ bws,  // frag-ordered fp8 centers, 128 KB
    const float* __restrict__ cnorm,        // [1024] fp32
    float* __restrict__ wsum) {

    __shared__ float bm[4][TROWS];           // per-wave keyed max per row
    __shared__ float nf_l[2][TROWS];         // per-tile row sumsq

    const int tid  = threadIdx.x;            // 0..255, 4 waves
    const int lane = tid & 63;
    const int w    = tid >> 6;
    const int tt   = w >> 1;                 // tile within block (0,1)
    const int hh   = w & 1;                  // center half (0,1)

    const int m16  = lane & 15;
    const int quad = lane >> 4;              // 0..3

    const int row0 = (blockIdx.x * 2 + tt) * TROWS;

    // ---- A fragments direct from global + row sumsq ----
    long long afr[4][4];                     // [i2][kk]
    float sq[4];
    #pragma unroll
    for (int i2 = 0; i2 < 4; ++i2) {
        const float* rp = feats + (size_t)(row0 + i2 * 16 + m16) * D + quad * 8;
        float a = 0.0f;
        #pragma unroll
        for (int kk = 0; kk < 4; ++kk) {
            float4 u = *(const float4*)(rp + kk * 32);
            float4 v = *(const float4*)(rp + kk * 32 + 4);
            unsigned int lo = pk_fp8<true>(u.z, u.w, pk_fp8<false>(u.x, u.y, 0u));
            unsigned int hi = pk_fp8<true>(v.z, v.w, pk_fp8<false>(v.x, v.y, 0u));
            afr[i2][kk] = (long long)(((unsigned long long)hi << 32) | (unsigned long long)lo);
            a += u.x*u.x + u.y*u.y + u.z*u.z + u.w*u.w;
            a += v.x*v.x + v.y*v.y + v.z*v.z + v.w*v.w;
        }
        sq[i2] = a;
    }
    #pragma unroll
    for (int i2 = 0; i2 < 4; ++i2) {         // reduce over quads (cols)
        sq[i2] += __shfl_xor(sq[i2], 16);
        sq[i2] += __shfl_xor(sq[i2], 32);
    }
    if (quad == 0 && hh == 0) {
        #pragma unroll
        for (int i2 = 0; i2 < 4; ++i2) nf_l[tt][i2 * 16 + m16] = sq[i2];
    }

    float best[16];                          // keyed floats, slot = i2*4 + r
    #pragma unroll
    for (int s = 0; s < 16; ++s) best[s] = -3.0e38f;

    // ---- sweep this wave's 512 centers: 16 pairs of 16-center groups ----
    const unsigned char* bbase = bws + (size_t)hh * 65536 + (size_t)lane * 32;
    #pragma unroll 2
    for (int it = 0; it < 16; ++it) {
        const unsigned char* p0 = bbase + (size_t)it * 4096;
        llx2 b0lo = *(const llx2*)(p0);
        llx2 b0hi = *(const llx2*)(p0 + 16);
        llx2 b1lo = *(const llx2*)(p0 + 2048);
        llx2 b1hi = *(const llx2*)(p0 + 2048 + 16);
        long long br0[4] = { b0lo[0], b0lo[1], b0hi[0], b0hi[1] };
        long long br1[4] = { b1lo[0], b1lo[1], b1hi[0], b1hi[1] };

        floatx4 acc[4][2];
        #pragma unroll
        for (int i2 = 0; i2 < 4; ++i2) {
            acc[i2][0] = (floatx4){0.f, 0.f, 0.f, 0.f};
            acc[i2][1] = (floatx4){0.f, 0.f, 0.f, 0.f};
        }
        #pragma unroll
        for (int kk = 0; kk < 4; ++kk)
            #pragma unroll
            for (int i2 = 0; i2 < 4; ++i2) {
                acc[i2][0] = __builtin_amdgcn_mfma_f32_16x16x32_fp8_fp8(
                    afr[i2][kk], br0[kk], acc[i2][0], 0, 0, 0);
                acc[i2][1] = __builtin_amdgcn_mfma_f32_16x16x32_fp8_fp8(
                    afr[i2][kk], br1[kk], acc[i2][1], 0, 0, 0);
            }

        const unsigned int inv0 = 1023u - (unsigned)(hh * 512 + it * 32 + m16);
        const unsigned int inv1 = inv0 - 16u;
        #pragma unroll
        for (int i2 = 0; i2 < 4; ++i2)
            #pragma unroll
            for (int r = 0; r < 4; ++r) {
                const int slot = i2 * 4 + r;
                best[slot] = fmaxf(best[slot],
                    fmaxf(key_pack(acc[i2][0][r], inv0),
                          key_pack(acc[i2][1][r], inv1)));
            }
    }

    // cross-m16 butterfly: per (quad,i2,r) max over this wave's centers
    #pragma unroll
    for (int mask = 1; mask <= 8; mask <<= 1)
        #pragma unroll
        for (int s = 0; s < 16; ++s)
            best[s] = fmaxf(best[s], __shfl_xor(best[s], mask));

    if (m16 == 0) {
        #pragma unroll
        for (int s = 0; s < 16; ++s) {
            int row = (s >> 2) * 16 + quad * 4 + (s & 3);
            bm[w][row] = best[s];
        }
    }
    __syncthreads();                         // bm + nf_l visible block-wide

    // ---- combine halves; decode; loss; reduce (even waves only) ----
    float partial = 0.0f;
    if (hh == 0) {
        const int row = lane;                // 64 rows on 64 lanes
        float kmax = fmaxf(bm[w][row], bm[w + 1][row]);
        unsigned int ub = __builtin_bit_cast(unsigned int, kmax);
        int   ka = 1023 - (int)(ub & 1023u);
        float d  = __builtin_bit_cast(float, (ub & 0xFFFFFC00u) | 0x200u);
        float nf = fmaxf(sqrtf(nf_l[tt][row]), 1e-12f);
        float na = cnorm[ka];
        float lsum = 1.0f - 2.0f * d * na / nf + na * na;
        #pragma unroll
        for (int m = 1; m <= 32; m <<= 1) lsum += __shfl_xor(lsum, m);
        partial = lsum;
    }
    if (lane == 0) wsum[blockIdx.x * 4 + w] = partial;
}

// ---- Final: sum 4096 per-wave partials -> out[0] ----
__global__ void reduce_out(const float* __restrict__ wsum,
                           float* __restrict__ out, int nW, float invN) {
    float s = 0.0f;
    for (int i = threadIdx.x; i < (nW >> 2); i += 256) {
        float4 v = ((const float4*)wsum)[i];
        s += (v.x + v.y) + (v.z + v.w);
    }
    #pragma unroll
    for (int m = 1; m <= 32; m <<= 1) s += __shfl_xor(s, m);
    __shared__ float ws4[4];
    if ((threadIdx.x & 63) == 0) ws4[threadIdx.x >> 6] = s;
    __syncthreads();
    if (threadIdx.x == 0)
        out[0] = ((ws4[0] + ws4[1]) + (ws4[2] + ws4[3])) * invN;
}

extern "C" void kernel_launch(void* const* d_in, const int* in_sizes, int n_in,
                              void* d_out, int out_size, void* d_ws, size_t ws_size,
                              hipStream_t stream) {
    const float* feats   = (const float*)d_in[0];
    const float* centers = (const float*)d_in[1];
    const int N = in_sizes[0] / D;   // 131072
    const int K = in_sizes[1] / D;   // 1024

    unsigned char* bws = (unsigned char*)d_ws;                     // 128 KB
    float* cnorm = (float*)((char*)d_ws + (size_t)K * D);          // 4 KB
    float* wsum  = (float*)((char*)d_ws + (size_t)K * D + 4096);   // 16 KB
    float* out = (float*)d_out;

    prep_centers<<<K, D, 0, stream>>>(centers, bws, cnorm);

    const int grid = (N / TROWS) / 2;        // 1024 blocks: 2 tiles x 2 halves
    cluster_main<<<grid, 256, 0, stream>>>(feats, bws, cnorm, wsum);

    reduce_out<<<1, 256, 0, stream>>>(wsum, out, grid * 4, 1.0f / (float)N);
}

// Round 9
// 117.852 us; speedup vs baseline: 1.0843x; 1.0843x over previous
//
#include <hip/hip_runtime.h>

// ClusterLoss fused kernel for MI355X (gfx950).  R16.
// Post-mortem R15 (53us): VGPR 92 crossed the 8->4 waves/SIMD bracket and the
// grid (4 blocks/CU exactly) had zero slack -> occupancy 17.6%. R14 (43us,
// VGPR 64) was ALSO starved: grid supplied only 16 waves/CU (measured ~10).
// Both are short of resident waves, not of intensity (B L2 traffic 15us
// overlaps the 16.6us MFMA floor).
// R16 = R14's verified pieces (LDS-staged swizzled A, frag-ordered bws sweep,
// keyed argmax) with the center sweep split across two waves per tile:
//   - 8192 waves, grid 2048 = 8 blocks/CU; at VGPR<=64 cap is 32 waves/CU ->
//     2x oversubscription for scheduling balance, 5-8 waves/SIMD latency hiding.
//   - registers: afr[2][4]+br 16+acc 16+best 8 ~ 56 live -> 64 bracket.
//   - A staged cooperatively by the whole block (feats read ONCE, coalesced),
//     one barrier; second barrier for the cross-half argmax combine.
// Allocator rules (measured): 1024-thr block or min-waves>=2 pins 64 VGPR.
// Use (256,1). Spill tripwire = WRITE_SIZE.
// loss_n = 1 - 2 d na/nf + na^2 (fp32 scalars).

#define D 128
#define TROWS 32

typedef __attribute__((ext_vector_type(4))) float floatx4;
typedef __attribute__((ext_vector_type(2))) long long llx2;

template <bool HI>
__device__ __forceinline__ unsigned int pk_fp8(float a, float b, unsigned int old) {
    return (unsigned int)__builtin_amdgcn_cvt_pk_fp8_f32(a, b, (int)old, HI);
}

__device__ __forceinline__ float key_pack(float v, unsigned int inv_k) {
    unsigned int u = __builtin_bit_cast(unsigned int, v);
    unsigned int r = (0x3FFu & inv_k) | (~0x3FFu & u);   // v_bfi_b32
    return __builtin_bit_cast(float, r);
}

// ---- Prep: normalize centers -> fp8, scattered into frag-ordered bws ----
// bws byte layout: ((g*64 + lane)*4 + kk)*8 + b  ==  chat[g*16 + (lane&15)]
//                                                    [kk*32 + (lane>>4)*8 + b]
__global__ void prep_centers(const float* __restrict__ centers,
                             unsigned char* __restrict__ bws,
                             float* __restrict__ cnorm) {
    const int k = blockIdx.x;
    const int t = threadIdx.x;            // 128 threads, one per dim
    float v = centers[(size_t)k * D + t];
    float s = v * v;
    #pragma unroll
    for (int m = 1; m <= 32; m <<= 1) s += __shfl_xor(s, m);
    __shared__ float ws2[2];
    if ((t & 63) == 0) ws2[t >> 6] = s;
    __syncthreads();
    float total = ws2[0] + ws2[1];
    float n = sqrtf(total);
    float q = v / fmaxf(n, 1e-12f);
    const int kk = t >> 5, quad = (t >> 3) & 3, b = t & 7;
    const int lane = (k & 15) + (quad << 4);
    const int g = k >> 4;
    bws[(((size_t)g * 64 + lane) * 4 + kk) * 8 + b] =
        (unsigned char)(pk_fp8<false>(q, q, 0u) & 0xFFu);
    if (t == 0) cnorm[k] = n;
}

// ---- Main: 4 waves = 2 tiles x 2 center-halves; two barriers total ----
__global__ __launch_bounds__(256, 1) void cluster_main(
    const float* __restrict__ feats,        // [N][128] fp32
    const unsigned char* __restrict__ bws,  // frag-ordered fp8 centers, 128 KB
    const float* __restrict__ cnorm,        // [1024] fp32
    float* __restrict__ wsum) {

    __shared__ unsigned char As[2][TROWS * D];   // swizzled fp8 A tiles, 8 KB
    __shared__ float nf_l[2][TROWS];
    __shared__ float bm[4][TROWS];

    const int tid  = threadIdx.x;            // 0..255, 4 waves
    const int lane = tid & 63;
    const int w    = tid >> 6;
    const int tt   = w >> 1;                 // tile within block (0,1)
    const int hh   = w & 1;                  // center half (0,1)

    const int m16  = lane & 15;
    const int quad = lane >> 4;              // 0..3
    const int q1   = quad >> 1, q0 = quad & 1;
    const int m8   = m16 & 7;

    // ---- Cooperative A staging: 256 thr = 32 rows x 8 chunks, per tile ----
    const int sr = tid >> 3;                 // row 0..31
    const int sc = tid & 7;                  // 16-float chunk 0..7
    #pragma unroll
    for (int t2 = 0; t2 < 2; ++t2) {
        const int row0 = (blockIdx.x * 2 + t2) * TROWS;
        const float4* src =
            (const float4*)(feats + (size_t)(row0 + sr) * D + sc * 16);
        float4 v0 = src[0], v1 = src[1], v2 = src[2], v3 = src[3];
        uint4 wd;
        wd.x = pk_fp8<true>(v0.z, v0.w, pk_fp8<false>(v0.x, v0.y, 0u));
        wd.y = pk_fp8<true>(v1.z, v1.w, pk_fp8<false>(v1.x, v1.y, 0u));
        wd.z = pk_fp8<true>(v2.z, v2.w, pk_fp8<false>(v2.x, v2.y, 0u));
        wd.w = pk_fp8<true>(v3.z, v3.w, pk_fp8<false>(v3.x, v3.y, 0u));
        *(uint4*)&As[t2][sr * D + ((sc ^ (sr & 7)) << 4)] = wd;
        float a = v0.x*v0.x + v0.y*v0.y + v0.z*v0.z + v0.w*v0.w;
        a += v1.x*v1.x + v1.y*v1.y + v1.z*v1.z + v1.w*v1.w;
        a += v2.x*v2.x + v2.y*v2.y + v2.z*v2.z + v2.w*v2.w;
        a += v3.x*v3.x + v3.y*v3.y + v3.z*v3.z + v3.w*v3.w;
        #pragma unroll
        for (int m = 1; m <= 4; m <<= 1) a += __shfl_xor(a, m);
        if (sc == 0) nf_l[t2][sr] = a;
    }
    __syncthreads();                         // As + nf_l visible block-wide

    // ---- A fragments (rows i2*16+m16 of tile tt) ----
    long long afr[2][4];
    #pragma unroll
    for (int i2 = 0; i2 < 2; ++i2) {
        const int r = i2 * 16 + m16;
        #pragma unroll
        for (int kk = 0; kk < 4; ++kk) {
            int pc = (2 * kk + q1) ^ m8;
            afr[i2][kk] = *(const long long*)&As[tt][r * D + pc * 16 + q0 * 8];
        }
    }

    float best[8];                           // keyed floats, slot = i2*4 + r
    #pragma unroll
    for (int s = 0; s < 8; ++s) best[s] = -3.0e38f;

    // ---- sweep this wave's 512 centers: 16 pairs of 16-center groups ----
    const unsigned char* bbase = bws + (size_t)hh * 65536 + (size_t)lane * 32;
    #pragma unroll 2
    for (int it = 0; it < 16; ++it) {
        const unsigned char* p0 = bbase + (size_t)it * 4096;
        llx2 b0lo = *(const llx2*)(p0);
        llx2 b0hi = *(const llx2*)(p0 + 16);
        llx2 b1lo = *(const llx2*)(p0 + 2048);
        llx2 b1hi = *(const llx2*)(p0 + 2048 + 16);
        long long br0[4] = { b0lo[0], b0lo[1], b0hi[0], b0hi[1] };
        long long br1[4] = { b1lo[0], b1lo[1], b1hi[0], b1hi[1] };

        floatx4 a00 = (floatx4){0.f,0.f,0.f,0.f};
        floatx4 a01 = (floatx4){0.f,0.f,0.f,0.f};
        floatx4 a10 = (floatx4){0.f,0.f,0.f,0.f};
        floatx4 a11 = (floatx4){0.f,0.f,0.f,0.f};
        #pragma unroll
        for (int kk = 0; kk < 4; ++kk) {
            a00 = __builtin_amdgcn_mfma_f32_16x16x32_fp8_fp8(afr[0][kk], br0[kk], a00, 0, 0, 0);
            a01 = __builtin_amdgcn_mfma_f32_16x16x32_fp8_fp8(afr[0][kk], br1[kk], a01, 0, 0, 0);
            a10 = __builtin_amdgcn_mfma_f32_16x16x32_fp8_fp8(afr[1][kk], br0[kk], a10, 0, 0, 0);
            a11 = __builtin_amdgcn_mfma_f32_16x16x32_fp8_fp8(afr[1][kk], br1[kk], a11, 0, 0, 0);
        }

        const unsigned int inv0 = 1023u - (unsigned)(hh * 512 + it * 32 + m16);
        const unsigned int inv1 = inv0 - 16u;
        #pragma unroll
        for (int r = 0; r < 4; ++r) {
            best[r]     = fmaxf(best[r],
                           fmaxf(key_pack(a00[r], inv0), key_pack(a01[r], inv1)));
            best[4 + r] = fmaxf(best[4 + r],
                           fmaxf(key_pack(a10[r], inv0), key_pack(a11[r], inv1)));
        }
    }

    // cross-m16 butterfly: per (quad,i2,r) max over this wave's centers
    #pragma unroll
    for (int mask = 1; mask <= 8; mask <<= 1)
        #pragma unroll
        for (int s = 0; s < 8; ++s)
            best[s] = fmaxf(best[s], __shfl_xor(best[s], mask));

    if (m16 == 0) {
        #pragma unroll
        for (int s = 0; s < 8; ++s) {
            int row = (s >> 2) * 16 + quad * 4 + (s & 3);
            bm[w][row] = best[s];
        }
    }
    __syncthreads();                         // bm visible block-wide

    // ---- combine halves; decode; loss; reduce (even waves only) ----
    float lsum = 0.0f;
    if (hh == 0 && lane < 32) {
        const int row = lane;                // 32 rows on 32 lanes
        float kmax = fmaxf(bm[w][row], bm[w + 1][row]);
        unsigned int ub = __builtin_bit_cast(unsigned int, kmax);
        int   ka = 1023 - (int)(ub & 1023u);
        float d  = __builtin_bit_cast(float, (ub & 0xFFFFFC00u) | 0x200u);
        float nf = fmaxf(sqrtf(nf_l[tt][row]), 1e-12f);
        float na = cnorm[ka];
        lsum = 1.0f - 2.0f * d * na / nf + na * na;
    }
    #pragma unroll
    for (int m = 1; m <= 16; m <<= 1) lsum += __shfl_xor(lsum, m);
    if (hh == 0 && lane == 0) wsum[blockIdx.x * 2 + tt] = lsum;
}

// ---- Final: sum 4096 per-tile partials -> out[0] ----
__global__ void reduce_out(const float* __restrict__ wsum,
                           float* __restrict__ out, int nW, float invN) {
    float s = 0.0f;
    for (int i = threadIdx.x; i < (nW >> 2); i += 256) {
        float4 v = ((const float4*)wsum)[i];
        s += (v.x + v.y) + (v.z + v.w);
    }
    #pragma unroll
    for (int m = 1; m <= 32; m <<= 1) s += __shfl_xor(s, m);
    __shared__ float ws4[4];
    if ((threadIdx.x & 63) == 0) ws4[threadIdx.x >> 6] = s;
    __syncthreads();
    if (threadIdx.x == 0)
        out[0] = ((ws4[0] + ws4[1]) + (ws4[2] + ws4[3])) * invN;
}

extern "C" void kernel_launch(void* const* d_in, const int* in_sizes, int n_in,
                              void* d_out, int out_size, void* d_ws, size_t ws_size,
                              hipStream_t stream) {
    const float* feats   = (const float*)d_in[0];
    const float* centers = (const float*)d_in[1];
    const int N = in_sizes[0] / D;   // 131072
    const int K = in_sizes[1] / D;   // 1024

    unsigned char* bws = (unsigned char*)d_ws;                     // 128 KB
    float* cnorm = (float*)((char*)d_ws + (size_t)K * D);          // 4 KB
    float* wsum  = (float*)((char*)d_ws + (size_t)K * D + 4096);   // 16 KB
    float* out = (float*)d_out;

    prep_centers<<<K, D, 0, stream>>>(centers, bws, cnorm);

    const int grid = (N / TROWS) / 2;        // 2048 blocks: 2 tiles x 2 halves
    cluster_main<<<grid, 256, 0, stream>>>(feats, bws, cnorm, wsum);

    reduce_out<<<1, 256, 0, stream>>>(wsum, out, grid * 2, 1.0f / (float)N);
}

// Round 10
// 117.623 us; speedup vs baseline: 1.0865x; 1.0019x over previous
//
#include <hip/hip_runtime.h>

// ClusterLoss fused kernel for MI355X (gfx950).  R17.
// Post-mortem R16: occupancy 22->46% with dur UNCHANGED (43->45us) => TLP is
// not the limiter. R14/R16 share the real bottleneck: the sweep loop's B
// loads (4x dwordx4) are serially ahead of each iteration's MFMA cluster;
// compiler drains vmcnt before the MFMAs -> ~250cyc L2 latency exposed per
// ~380cyc iteration, matrix pipe idle ~54% (MfmaUtil 28%).
// R17 = R16 + depth-1 software pipeline on the B stream: two NAMED register
// sets (static indexing, zero copies); next pair-group's loads issue before
// the current group's MFMAs -> latency covered by ~380cyc of work, counted
// vmcnt keeps one set in flight. +16 VGPR (~72-84 total): crosses into the
// 4-waves/SIMD bracket, acceptable since measured residency is already ~3.7
// blocks/CU and grid=8 blocks/CU keeps slack (R15's failure was no-slack
// grid, not the bracket alone).
// Allocator rules (measured): 1024-thr block or min-waves>=2 pins 64 VGPR.
// Use (256,1). Spill tripwire = WRITE_SIZE.
// loss_n = 1 - 2 d na/nf + na^2 (fp32 scalars).

#define D 128
#define TROWS 32

typedef __attribute__((ext_vector_type(4))) float floatx4;
typedef __attribute__((ext_vector_type(2))) long long llx2;

template <bool HI>
__device__ __forceinline__ unsigned int pk_fp8(float a, float b, unsigned int old) {
    return (unsigned int)__builtin_amdgcn_cvt_pk_fp8_f32(a, b, (int)old, HI);
}

__device__ __forceinline__ float key_pack(float v, unsigned int inv_k) {
    unsigned int u = __builtin_bit_cast(unsigned int, v);
    unsigned int r = (0x3FFu & inv_k) | (~0x3FFu & u);   // v_bfi_b32
    return __builtin_bit_cast(float, r);
}

// ---- Prep: normalize centers -> fp8, scattered into frag-ordered bws ----
// bws byte layout: ((g*64 + lane)*4 + kk)*8 + b  ==  chat[g*16 + (lane&15)]
//                                                    [kk*32 + (lane>>4)*8 + b]
__global__ void prep_centers(const float* __restrict__ centers,
                             unsigned char* __restrict__ bws,
                             float* __restrict__ cnorm) {
    const int k = blockIdx.x;
    const int t = threadIdx.x;            // 128 threads, one per dim
    float v = centers[(size_t)k * D + t];
    float s = v * v;
    #pragma unroll
    for (int m = 1; m <= 32; m <<= 1) s += __shfl_xor(s, m);
    __shared__ float ws2[2];
    if ((t & 63) == 0) ws2[t >> 6] = s;
    __syncthreads();
    float total = ws2[0] + ws2[1];
    float n = sqrtf(total);
    float q = v / fmaxf(n, 1e-12f);
    const int kk = t >> 5, quad = (t >> 3) & 3, b = t & 7;
    const int lane = (k & 15) + (quad << 4);
    const int g = k >> 4;
    bws[(((size_t)g * 64 + lane) * 4 + kk) * 8 + b] =
        (unsigned char)(pk_fp8<false>(q, q, 0u) & 0xFFu);
    if (t == 0) cnorm[k] = n;
}

// ---- Main: 4 waves = 2 tiles x 2 center-halves; two barriers total ----
__global__ __launch_bounds__(256, 1) void cluster_main(
    const float* __restrict__ feats,        // [N][128] fp32
    const unsigned char* __restrict__ bws,  // frag-ordered fp8 centers, 128 KB
    const float* __restrict__ cnorm,        // [1024] fp32
    float* __restrict__ wsum) {

    __shared__ unsigned char As[2][TROWS * D];   // swizzled fp8 A tiles, 8 KB
    __shared__ float nf_l[2][TROWS];
    __shared__ float bm[4][TROWS];

    const int tid  = threadIdx.x;            // 0..255, 4 waves
    const int lane = tid & 63;
    const int w    = tid >> 6;
    const int tt   = w >> 1;                 // tile within block (0,1)
    const int hh   = w & 1;                  // center half (0,1)

    const int m16  = lane & 15;
    const int quad = lane >> 4;              // 0..3
    const int q1   = quad >> 1, q0 = quad & 1;
    const int m8   = m16 & 7;

    // ---- Cooperative A staging: 256 thr = 32 rows x 8 chunks, per tile ----
    const int sr = tid >> 3;                 // row 0..31
    const int sc = tid & 7;                  // 16-float chunk 0..7
    #pragma unroll
    for (int t2 = 0; t2 < 2; ++t2) {
        const int row0 = (blockIdx.x * 2 + t2) * TROWS;
        const float4* src =
            (const float4*)(feats + (size_t)(row0 + sr) * D + sc * 16);
        float4 v0 = src[0], v1 = src[1], v2 = src[2], v3 = src[3];
        uint4 wd;
        wd.x = pk_fp8<true>(v0.z, v0.w, pk_fp8<false>(v0.x, v0.y, 0u));
        wd.y = pk_fp8<true>(v1.z, v1.w, pk_fp8<false>(v1.x, v1.y, 0u));
        wd.z = pk_fp8<true>(v2.z, v2.w, pk_fp8<false>(v2.x, v2.y, 0u));
        wd.w = pk_fp8<true>(v3.z, v3.w, pk_fp8<false>(v3.x, v3.y, 0u));
        *(uint4*)&As[t2][sr * D + ((sc ^ (sr & 7)) << 4)] = wd;
        float a = v0.x*v0.x + v0.y*v0.y + v0.z*v0.z + v0.w*v0.w;
        a += v1.x*v1.x + v1.y*v1.y + v1.z*v1.z + v1.w*v1.w;
        a += v2.x*v2.x + v2.y*v2.y + v2.z*v2.z + v2.w*v2.w;
        a += v3.x*v3.x + v3.y*v3.y + v3.z*v3.z + v3.w*v3.w;
        #pragma unroll
        for (int m = 1; m <= 4; m <<= 1) a += __shfl_xor(a, m);
        if (sc == 0) nf_l[t2][sr] = a;
    }
    __syncthreads();                         // As + nf_l visible block-wide

    // ---- A fragments (rows i2*16+m16 of tile tt) ----
    long long afr[2][4];
    #pragma unroll
    for (int i2 = 0; i2 < 2; ++i2) {
        const int r = i2 * 16 + m16;
        #pragma unroll
        for (int kk = 0; kk < 4; ++kk) {
            int pc = (2 * kk + q1) ^ m8;
            afr[i2][kk] = *(const long long*)&As[tt][r * D + pc * 16 + q0 * 8];
        }
    }

    float best[8];                           // keyed floats, slot = i2*4 + r
    #pragma unroll
    for (int s = 0; s < 8; ++s) best[s] = -3.0e38f;

    const unsigned char* bbase = bws + (size_t)hh * 65536 + (size_t)lane * 32;

    // one pair-group (2x16 centers): 4 dwordx4 in regs
    auto loadB = [&](int it, llx2& lo0, llx2& hi0, llx2& lo1, llx2& hi1) {
        const unsigned char* p = bbase + (size_t)it * 4096;
        lo0 = *(const llx2*)(p);
        hi0 = *(const llx2*)(p + 16);
        lo1 = *(const llx2*)(p + 2048);
        hi1 = *(const llx2*)(p + 2048 + 16);
    };
    auto stepB = [&](int it, llx2 lo0, llx2 hi0, llx2 lo1, llx2 hi1) {
        long long br0[4] = { lo0[0], lo0[1], hi0[0], hi0[1] };  // names only
        long long br1[4] = { lo1[0], lo1[1], hi1[0], hi1[1] };
        floatx4 a00 = (floatx4){0.f,0.f,0.f,0.f};
        floatx4 a01 = (floatx4){0.f,0.f,0.f,0.f};
        floatx4 a10 = (floatx4){0.f,0.f,0.f,0.f};
        floatx4 a11 = (floatx4){0.f,0.f,0.f,0.f};
        #pragma unroll
        for (int kk = 0; kk < 4; ++kk) {
            a00 = __builtin_amdgcn_mfma_f32_16x16x32_fp8_fp8(afr[0][kk], br0[kk], a00, 0, 0, 0);
            a01 = __builtin_amdgcn_mfma_f32_16x16x32_fp8_fp8(afr[0][kk], br1[kk], a01, 0, 0, 0);
            a10 = __builtin_amdgcn_mfma_f32_16x16x32_fp8_fp8(afr[1][kk], br0[kk], a10, 0, 0, 0);
            a11 = __builtin_amdgcn_mfma_f32_16x16x32_fp8_fp8(afr[1][kk], br1[kk], a11, 0, 0, 0);
        }
        const unsigned int inv0 = 1023u - (unsigned)(hh * 512 + it * 32 + m16);
        const unsigned int inv1 = inv0 - 16u;
        #pragma unroll
        for (int r = 0; r < 4; ++r) {
            best[r]     = fmaxf(best[r],
                           fmaxf(key_pack(a00[r], inv0), key_pack(a01[r], inv1)));
            best[4 + r] = fmaxf(best[4 + r],
                           fmaxf(key_pack(a10[r], inv0), key_pack(a11[r], inv1)));
        }
    };

    // ---- sweep 512 centers: 16 pair-groups, depth-1 pipelined ----
    llx2 xlo0, xhi0, xlo1, xhi1;             // set X (even its)
    llx2 ylo0, yhi0, ylo1, yhi1;             // set Y (odd its)
    loadB(0, xlo0, xhi0, xlo1, xhi1);
    #pragma unroll 1
    for (int it2 = 0; it2 < 8; ++it2) {
        loadB(2 * it2 + 1, ylo0, yhi0, ylo1, yhi1);   // in flight during X
        stepB(2 * it2,     xlo0, xhi0, xlo1, xhi1);
        if (it2 < 7)
            loadB(2 * it2 + 2, xlo0, xhi0, xlo1, xhi1); // in flight during Y
        stepB(2 * it2 + 1, ylo0, yhi0, ylo1, yhi1);
    }

    // cross-m16 butterfly: per (quad,i2,r) max over this wave's centers
    #pragma unroll
    for (int mask = 1; mask <= 8; mask <<= 1)
        #pragma unroll
        for (int s = 0; s < 8; ++s)
            best[s] = fmaxf(best[s], __shfl_xor(best[s], mask));

    if (m16 == 0) {
        #pragma unroll
        for (int s = 0; s < 8; ++s) {
            int row = (s >> 2) * 16 + quad * 4 + (s & 3);
            bm[w][row] = best[s];
        }
    }
    __syncthreads();                         // bm visible block-wide

    // ---- combine halves; decode; loss; reduce (even waves only) ----
    float lsum = 0.0f;
    if (hh == 0 && lane < 32) {
        const int row = lane;                // 32 rows on 32 lanes
        float kmax = fmaxf(bm[w][row], bm[w + 1][row]);
        unsigned int ub = __builtin_bit_cast(unsigned int, kmax);
        int   ka = 1023 - (int)(ub & 1023u);
        float d  = __builtin_bit_cast(float, (ub & 0xFFFFFC00u) | 0x200u);
        float nf = fmaxf(sqrtf(nf_l[tt][row]), 1e-12f);
        float na = cnorm[ka];
        lsum = 1.0f - 2.0f * d * na / nf + na * na;
    }
    #pragma unroll
    for (int m = 1; m <= 16; m <<= 1) lsum += __shfl_xor(lsum, m);
    if (hh == 0 && lane == 0) wsum[blockIdx.x * 2 + tt] = lsum;
}

// ---- Final: sum 4096 per-tile partials -> out[0] ----
__global__ void reduce_out(const float* __restrict__ wsum,
                           float* __restrict__ out, int nW, float invN) {
    float s = 0.0f;
    for (int i = threadIdx.x; i < (nW >> 2); i += 256) {
        float4 v = ((const float4*)wsum)[i];
        s += (v.x + v.y) + (v.z + v.w);
    }
    #pragma unroll
    for (int m = 1; m <= 32; m <<= 1) s += __shfl_xor(s, m);
    __shared__ float ws4[4];
    if ((threadIdx.x & 63) == 0) ws4[threadIdx.x >> 6] = s;
    __syncthreads();
    if (threadIdx.x == 0)
        out[0] = ((ws4[0] + ws4[1]) + (ws4[2] + ws4[3])) * invN;
}

extern "C" void kernel_launch(void* const* d_in, const int* in_sizes, int n_in,
                              void* d_out, int out_size, void* d_ws, size_t ws_size,
                              hipStream_t stream) {
    const float* feats   = (const float*)d_in[0];
    const float* centers = (const float*)d_in[1];
    const int N = in_sizes[0] / D;   // 131072
    const int K = in_sizes[1] / D;   // 1024

    unsigned char* bws = (unsigned char*)d_ws;                     // 128 KB
    float* cnorm = (float*)((char*)d_ws + (size_t)K * D);          // 4 KB
    float* wsum  = (float*)((char*)d_ws + (size_t)K * D + 4096);   // 16 KB
    float* out = (float*)d_out;

    prep_centers<<<K, D, 0, stream>>>(centers, bws, cnorm);

    const int grid = (N / TROWS) / 2;        // 2048 blocks: 2 tiles x 2 halves
    cluster_main<<<grid, 256, 0, stream>>>(feats, bws, cnorm, wsum);

    reduce_out<<<1, 256, 0, stream>>>(wsum, out, grid * 2, 1.0f / (float)N);
}